// Round 3
// baseline (93.087 us; speedup 1.0000x reference)
//
#include <hip/hip_runtime.h>
#include <stdint.h>

typedef __bf16 bf16;
typedef bf16 bf16x8 __attribute__((ext_vector_type(8)));
typedef bf16 bf16x4 __attribute__((ext_vector_type(4)));
typedef float f32x4 __attribute__((ext_vector_type(4)));

#define NB 8
#define NS 1024
#define NC 512
#define NH 8
#define ND 64

// q pre-scale: dim_head^-0.5 * log2(e) so attention uses exp2 directly
#define QSCALE 0.18033688011f

__device__ __forceinline__ void gload16(const void* g, void* l) {
  __builtin_amdgcn_global_load_lds(
      (const __attribute__((address_space(1))) void*)g,
      (__attribute__((address_space(3))) void*)l, 16, 0, 0);
}

// ---------------- 1) BN(eval) + transpose: x[b][c][s] -> t[b][s][c] bf16 ----
__global__ __launch_bounds__(256) void bn_tr_kernel(
    const float* __restrict__ x, const float* __restrict__ gam,
    const float* __restrict__ bet, const float* __restrict__ mu,
    const float* __restrict__ var, bf16* __restrict__ t) {
  __shared__ float tile[32][33];
  const int b = blockIdx.z, c0 = blockIdx.y * 32, s0 = blockIdx.x * 32;
  const int tx = threadIdx.x, sj = tx & 31, ci = tx >> 5;
#pragma unroll
  for (int kk = 0; kk < 4; ++kk) {
    const int c = c0 + ci + (kk << 3);
    const float sc = gam[c] * rsqrtf(var[c] + 1e-5f);
    const float sh = bet[c] - mu[c] * sc;
    tile[ci + (kk << 3)][sj] = x[(size_t)(b * NC + c) * NS + s0 + sj] * sc + sh;
  }
  __syncthreads();
#pragma unroll
  for (int kk = 0; kk < 4; ++kk) {
    const int s = s0 + ci + (kk << 3);
    t[(size_t)(b * NS + s) * NC + c0 + sj] = (bf16)tile[sj][ci + (kk << 3)];
  }
}

// ---------------- 2) weights f32 -> bf16 (vectorized) -----------------------
__global__ __launch_bounds__(256) void wconv_kernel(
    const float* __restrict__ wq, const float* __restrict__ wk,
    const float* __restrict__ wv, const float* __restrict__ wo,
    bf16* __restrict__ wqb, bf16* __restrict__ wkb, bf16* __restrict__ wvb,
    bf16* __restrict__ wob) {
  const int i = (blockIdx.x * 256 + threadIdx.x) * 4;
  float4 a = *(const float4*)(&wq[i]);
  float4 b = *(const float4*)(&wk[i]);
  float4 c = *(const float4*)(&wv[i]);
  float4 d = *(const float4*)(&wo[i]);
  bf16x4 av = {(bf16)a.x, (bf16)a.y, (bf16)a.z, (bf16)a.w};
  bf16x4 bv = {(bf16)b.x, (bf16)b.y, (bf16)b.z, (bf16)b.w};
  bf16x4 cv = {(bf16)c.x, (bf16)c.y, (bf16)c.z, (bf16)c.w};
  bf16x4 dv = {(bf16)d.x, (bf16)d.y, (bf16)d.z, (bf16)d.w};
  *(bf16x4*)(&wqb[i]) = av;
  *(bf16x4*)(&wkb[i]) = bv;
  *(bf16x4*)(&wvb[i]) = cv;
  *(bf16x4*)(&wob[i]) = dv;
}

// ---------------- 3) QKV GEMM (double-buffered) -----------------------------
// m = (b,s) over 8192, n picks {wq,wk,wv}. Q/K: swapped operands -> C[w][s],
// lane packs 4 consecutive d -> bf16x4 stores to [B][H][S][D].
// V: unswapped -> lane packs 4 consecutive s -> bf16x4 stores to [B][H][D][S].
__global__ __launch_bounds__(256) void gemm_qkv_kernel(
    const bf16* __restrict__ t, const bf16* __restrict__ wqb,
    const bf16* __restrict__ wkb, const bf16* __restrict__ wvb,
    const float* __restrict__ bq, const float* __restrict__ bk,
    const float* __restrict__ bv, bf16* __restrict__ qo, bf16* __restrict__ ko,
    bf16* __restrict__ vo) {
  __shared__ __align__(16) bf16 As[2][128 * 32];
  __shared__ __align__(16) bf16 Bs[2][128 * 32];
  const int tid = threadIdx.x;
  const int m0 = blockIdx.x * 128, n0 = blockIdx.y * 128;
  const int wsel = n0 >> 9;
  const bf16* W = (wsel == 0) ? wqb : (wsel == 1 ? wkb : wvb);
  const float* bias = (wsel == 0) ? bq : (wsel == 1 ? bk : bv);
  const int nb = n0 & 511;
  const int w = tid >> 6, lane = tid & 63, l15 = lane & 15, l4 = lane >> 4;
  const int wm = (w >> 1) << 6, wn = (w & 1) << 6;

  // staging geometry: linear LDS dest, inverse-swizzled global source
  const int srl = lane >> 2, sp = lane & 3;
  const int r0 = w * 16 + srl, r1 = 64 + w * 16 + srl;
  const int c0off = (sp ^ ((r0 >> 1) & 3)) << 3;
  const int c1off = (sp ^ ((r1 >> 1) & 3)) << 3;
  const bf16* a0 = t + (size_t)(m0 + r0) * 512 + c0off;
  const bf16* a1 = t + (size_t)(m0 + r1) * 512 + c1off;
  const bf16* b0 = W + (size_t)(nb + r0) * 512 + c0off;
  const bf16* b1 = W + (size_t)(nb + r1) * 512 + c1off;

  f32x4 acc[4][4] = {};
  // prologue stage
  gload16(a0, &As[0][w * 512]);
  gload16(a1, &As[0][2048 + w * 512]);
  gload16(b0, &Bs[0][w * 512]);
  gload16(b1, &Bs[0][2048 + w * 512]);
  __syncthreads();
  int buf = 0;
  for (int k0 = 0; k0 < 512; k0 += 32, buf ^= 1) {
    if (k0 + 32 < 512) {
      gload16(a0 + k0 + 32, &As[buf ^ 1][w * 512]);
      gload16(a1 + k0 + 32, &As[buf ^ 1][2048 + w * 512]);
      gload16(b0 + k0 + 32, &Bs[buf ^ 1][w * 512]);
      gload16(b1 + k0 + 32, &Bs[buf ^ 1][2048 + w * 512]);
    }
    bf16x8 af[4], bfv[4];
#pragma unroll
    for (int mi = 0; mi < 4; ++mi) {
      const int row = wm + mi * 16 + l15;
      af[mi] = *(const bf16x8*)(&As[buf][row * 32 + ((l4 ^ ((row >> 1) & 3)) << 3)]);
    }
#pragma unroll
    for (int ni = 0; ni < 4; ++ni) {
      const int row = wn + ni * 16 + l15;
      bfv[ni] = *(const bf16x8*)(&Bs[buf][row * 32 + ((l4 ^ ((row >> 1) & 3)) << 3)]);
    }
    if (wsel == 2) {
#pragma unroll
      for (int mi = 0; mi < 4; ++mi)
#pragma unroll
        for (int ni = 0; ni < 4; ++ni)
          acc[mi][ni] = __builtin_amdgcn_mfma_f32_16x16x32_bf16(
              af[mi], bfv[ni], acc[mi][ni], 0, 0, 0);
    } else {
#pragma unroll
      for (int mi = 0; mi < 4; ++mi)
#pragma unroll
        for (int ni = 0; ni < 4; ++ni)
          acc[mi][ni] = __builtin_amdgcn_mfma_f32_16x16x32_bf16(
              bfv[ni], af[mi], acc[mi][ni], 0, 0, 0);
    }
    __syncthreads();
  }
  const int bidx = m0 >> 10;
  if (wsel == 2) {
    // V (unswapped): row = s = wm+mi*16+(l4<<2)+r, col = l15 -> nn
    const int sbase = (m0 & 1023) + wm + (l4 << 2);
#pragma unroll
    for (int ni = 0; ni < 4; ++ni) {
      const int nn = nb + wn + ni * 16 + l15;
      const int hh = nn >> 6, dd = nn & 63;
      const float bsv = bias[nn];
      bf16* vbase = vo + (size_t)(bidx * NH + hh) * (ND * NS) + (size_t)dd * NS + sbase;
#pragma unroll
      for (int mi = 0; mi < 4; ++mi) {
        bf16x4 pk;
#pragma unroll
        for (int r = 0; r < 4; ++r) pk[r] = (bf16)(acc[mi][ni][r] + bsv);
        *(bf16x4*)(&vbase[mi * 16]) = pk;
      }
    }
  } else {
    // Q/K (swapped): row = W-dim = nb+wn+ni*16+(l4<<2)+r, col = s = m0+wm+mi*16+l15
    const bool isq = (wsel == 0);
    bf16* outp = isq ? qo : ko;
    const int sbase = (m0 & 1023) + wm + l15;
#pragma unroll
    for (int ni = 0; ni < 4; ++ni) {
      const int nn0 = nb + wn + ni * 16 + (l4 << 2);
      const int hh = nn0 >> 6, dd0 = nn0 & 63;
      const float4 bs4 = *(const float4*)(&bias[nn0]);
      bf16* obase = outp + (size_t)(bidx * NH + hh) * (NS * ND) + dd0;
#pragma unroll
      for (int mi = 0; mi < 4; ++mi) {
        bf16x4 pk;
        const float* bp = (const float*)&bs4;
#pragma unroll
        for (int r = 0; r < 4; ++r) {
          float val = acc[mi][ni][r] + bp[r];
          if (isq) val *= QSCALE;
          pk[r] = (bf16)val;
        }
        *(bf16x4*)(&obase[(size_t)(sbase + mi * 16) * ND]) = pk;
      }
    }
  }
}

// ---------------- 4) flash attention, KVBLK=128 ------------------------------
// grid (S/128, B*H), 8 waves; wave w owns q-rows [w*16, w*16+16).
// Swapped QK^T (lane owns q-row l15's scores) and swapped PV (O^T: lane packs
// 4 consecutive d, alpha/l are lane-local).
__global__ __launch_bounds__(512, 4) void attn_kernel(
    const bf16* __restrict__ qg, const bf16* __restrict__ kg,
    const bf16* __restrict__ vtg, bf16* __restrict__ og) {
  __shared__ __align__(16) bf16 Kb[2][128 * 64];  // [kv][d]
  __shared__ __align__(16) bf16 Vb[2][64 * 128];  // [d][kv]
  __shared__ __align__(16) bf16 Ps[8][16 * 64];   // per-wave P half (16q x 64kv)
  const int bh = blockIdx.y, q0 = blockIdx.x * 128;
  const int tid = threadIdx.x, w = tid >> 6, lane = tid & 63;
  const int l15 = lane & 15, l4 = lane >> 4, l7 = l15 & 7;
  const bf16* Qp = qg + ((size_t)bh * NS + q0) * ND;
  const bf16* Kp = kg + (size_t)bh * NS * ND;
  const bf16* Vp = vtg + (size_t)bh * ND * NS;

  // Q frags straight from global
  bf16x8 qf[2];
#pragma unroll
  for (int kk = 0; kk < 2; ++kk)
    qf[kk] = *(const bf16x8*)(&Qp[(size_t)(w * 16 + l15) * ND + ((kk << 2) + l4) * 8]);

  // staging lane geometry (inverse-swizzled global source, linear LDS dest)
  const int krow = w * 8 + (lane >> 3);
  const int kcol = ((lane & 7) ^ (krow & 7)) << 3;
  const bf16* ksrc = Kp + (size_t)krow * ND + kcol;
  const int vrow = w * 4 + (lane >> 4);
  const int vcol = ((lane & 15) ^ (vrow & 7)) << 3;
  const bf16* vsrc = Vp + (size_t)vrow * NS + vcol;

  f32x4 oacc[4] = {};
  float mrun = -1e30f, lrun = 0.f;

  // prologue: stage tile 0
  gload16(ksrc, &Kb[0][w * 512]);
  gload16(ksrc + (size_t)64 * ND, &Kb[0][4096 + w * 512]);
  gload16(vsrc, &Vb[0][w * 512]);
  gload16(vsrc + (size_t)32 * NS, &Vb[0][4096 + w * 512]);
  __syncthreads();

  const int kb0 = l15 * 64 + ((l4 ^ l7) << 3);
  const int kb1 = l15 * 64 + (((4 + l4) ^ l7) << 3);
  int buf = 0;
  for (int kv0 = 0; kv0 < NS; kv0 += 128, buf ^= 1) {
    if (kv0 + 128 < NS) {
      gload16(ksrc + (size_t)(kv0 + 128) * ND, &Kb[buf ^ 1][w * 512]);
      gload16(ksrc + (size_t)(kv0 + 192) * ND, &Kb[buf ^ 1][4096 + w * 512]);
      gload16(vsrc + (kv0 + 128), &Vb[buf ^ 1][w * 512]);
      gload16(vsrc + (size_t)32 * NS + (kv0 + 128), &Vb[buf ^ 1][4096 + w * 512]);
    }
    const bf16* Ks = Kb[buf];
    const bf16* Vs = Vb[buf];
    // S^T: st[rt][r] = score(kv = rt*16 + l4*4 + r, q = l15)
    f32x4 st[8];
    __builtin_amdgcn_s_setprio(1);
#pragma unroll
    for (int rt = 0; rt < 8; ++rt) {
      const bf16x8 a0 = *(const bf16x8*)(&Ks[rt * 1024 + kb0]);
      const bf16x8 a1 = *(const bf16x8*)(&Ks[rt * 1024 + kb1]);
      f32x4 z = {0.f, 0.f, 0.f, 0.f};
      z = __builtin_amdgcn_mfma_f32_16x16x32_bf16(a0, qf[0], z, 0, 0, 0);
      st[rt] = __builtin_amdgcn_mfma_f32_16x16x32_bf16(a1, qf[1], z, 0, 0, 0);
    }
    __builtin_amdgcn_s_setprio(0);
    // online softmax for q-row l15 (32 in-lane + cross-l4 reduce)
    float pm = -1e30f;
#pragma unroll
    for (int rt = 0; rt < 8; ++rt)
#pragma unroll
      for (int r = 0; r < 4; ++r) pm = fmaxf(pm, st[rt][r]);
    pm = fmaxf(pm, __shfl_xor(pm, 16));
    pm = fmaxf(pm, __shfl_xor(pm, 32));
    // defer-max (T13): skip rescale while growth <= 8 (log2 domain, P <= 256)
    if (!__all(pm - mrun <= 8.f)) {
      const float mnew = fmaxf(mrun, pm);
      const float alpha = __builtin_amdgcn_exp2f(mrun - mnew);
      // col = q = l15 -> alpha is lane-local for every acc element
#pragma unroll
      for (int di = 0; di < 4; ++di)
#pragma unroll
        for (int r = 0; r < 4; ++r) oacc[di][r] *= alpha;
      lrun *= alpha;
      mrun = mnew;
    }
    float rs = 0.f;
    // two 64-kv halves, reusing Ps[w]
#pragma unroll
    for (int h = 0; h < 2; ++h) {
#pragma unroll
      for (int rt4 = 0; rt4 < 4; ++rt4) {
        const int rt = h * 4 + rt4;
        bf16x4 pk;
#pragma unroll
        for (int r = 0; r < 4; ++r) {
          const float p = __builtin_amdgcn_exp2f(st[rt][r] - mrun);
          rs += p;
          pk[r] = (bf16)p;
        }
        const int slot = (rt4 << 1) + (l4 >> 1);
        *(bf16x4*)(&Ps[w][l15 * 64 + ((slot ^ l7) << 3) + ((l4 & 1) << 2)]) = pk;
      }
      bf16x8 pa0 = *(const bf16x8*)(&Ps[w][l15 * 64 + ((l4 ^ l7) << 3)]);
      bf16x8 pa1 = *(const bf16x8*)(&Ps[w][l15 * 64 + (((4 + l4) ^ l7) << 3)]);
      __builtin_amdgcn_s_setprio(1);
#pragma unroll
      for (int di = 0; di < 4; ++di) {
        const int vb = (di * 16 + l15) * 128;
        const bf16x8 v0 =
            *(const bf16x8*)(&Vs[vb + ((((h << 3) + l4) ^ l7) << 3)]);
        const bf16x8 v1 =
            *(const bf16x8*)(&Vs[vb + ((((h << 3) + 4 + l4) ^ l7) << 3)]);
        oacc[di] = __builtin_amdgcn_mfma_f32_16x16x32_bf16(v0, pa0, oacc[di], 0, 0, 0);
        oacc[di] = __builtin_amdgcn_mfma_f32_16x16x32_bf16(v1, pa1, oacc[di], 0, 0, 0);
      }
      __builtin_amdgcn_s_setprio(0);
    }
    lrun += rs;
    __syncthreads();  // drains next-tile loads + protects buffer swap
  }
  // final l reduce across l4 groups, then lane-local normalize
  lrun += __shfl_xor(lrun, 16);
  lrun += __shfl_xor(lrun, 32);
  const float linv = 1.f / lrun;
  const int b = bh >> 3, h = bh & 7;
  // O^T: lane holds q = l15 (col), d = di*16 + (l4<<2) + r (rows) -> packed
  bf16* Op = og + (size_t)(b * NS + q0 + w * 16 + l15) * NC + h * ND + (l4 << 2);
#pragma unroll
  for (int di = 0; di < 4; ++di) {
    bf16x4 pk;
#pragma unroll
    for (int r = 0; r < 4; ++r) pk[r] = (bf16)(oacc[di][r] * linv);
    *(bf16x4*)(&Op[di * 16]) = pk;
  }
}

// ---------------- 5) out GEMM (double-buffered, swapped) ---------------------
// C[s][cout]: lane packs 4 consecutive s -> float4 stores to [b][cout][s].
__global__ __launch_bounds__(256) void gemm_out_kernel(
    const bf16* __restrict__ wob, const bf16* __restrict__ o,
    const float* __restrict__ bo, float* __restrict__ out) {
  __shared__ __align__(16) bf16 As[2][128 * 32];
  __shared__ __align__(16) bf16 Bs[2][128 * 32];
  const int tid = threadIdx.x;
  const int m0 = blockIdx.x * 128, n0 = blockIdx.y * 128;
  const int w = tid >> 6, lane = tid & 63, l15 = lane & 15, l4 = lane >> 4;
  const int wm = (w >> 1) << 6, wn = (w & 1) << 6;

  const int srl = lane >> 2, sp = lane & 3;
  const int r0 = w * 16 + srl, r1 = 64 + w * 16 + srl;
  const int c0off = (sp ^ ((r0 >> 1) & 3)) << 3;
  const int c1off = (sp ^ ((r1 >> 1) & 3)) << 3;
  const bf16* a0 = wob + (size_t)(m0 + r0) * 512 + c0off;
  const bf16* a1 = wob + (size_t)(m0 + r1) * 512 + c1off;
  const bf16* b0 = o + (size_t)(n0 + r0) * 512 + c0off;
  const bf16* b1 = o + (size_t)(n0 + r1) * 512 + c1off;

  f32x4 acc[4][4] = {};
  gload16(a0, &As[0][w * 512]);
  gload16(a1, &As[0][2048 + w * 512]);
  gload16(b0, &Bs[0][w * 512]);
  gload16(b1, &Bs[0][2048 + w * 512]);
  __syncthreads();
  int buf = 0;
  for (int k0 = 0; k0 < 512; k0 += 32, buf ^= 1) {
    if (k0 + 32 < 512) {
      gload16(a0 + k0 + 32, &As[buf ^ 1][w * 512]);
      gload16(a1 + k0 + 32, &As[buf ^ 1][2048 + w * 512]);
      gload16(b0 + k0 + 32, &Bs[buf ^ 1][w * 512]);
      gload16(b1 + k0 + 32, &Bs[buf ^ 1][2048 + w * 512]);
    }
    bf16x8 af[4], bfv[4];
#pragma unroll
    for (int mi = 0; mi < 4; ++mi) {
      const int row = wm + mi * 16 + l15;
      af[mi] = *(const bf16x8*)(&As[buf][row * 32 + ((l4 ^ ((row >> 1) & 3)) << 3)]);
    }
#pragma unroll
    for (int ni = 0; ni < 4; ++ni) {
      const int row = wn + ni * 16 + l15;
      bfv[ni] = *(const bf16x8*)(&Bs[buf][row * 32 + ((l4 ^ ((row >> 1) & 3)) << 3)]);
    }
#pragma unroll
    for (int mi = 0; mi < 4; ++mi)
#pragma unroll
      for (int ni = 0; ni < 4; ++ni)
        acc[mi][ni] = __builtin_amdgcn_mfma_f32_16x16x32_bf16(
            bfv[ni], af[mi], acc[mi][ni], 0, 0, 0);
    __syncthreads();
  }
  const int b = n0 >> 10;
  const int sb = (n0 & 1023) + wn;
#pragma unroll
  for (int mi = 0; mi < 4; ++mi) {
    const int cout = m0 + wm + mi * 16 + l15;
    const float bsv = bo[cout];
    float* obase = out + (size_t)(b * NC + cout) * NS;
#pragma unroll
    for (int ni = 0; ni < 4; ++ni) {
      const int s0i = sb + ni * 16 + (l4 << 2);
      float4 pk = {acc[mi][ni][0] + bsv, acc[mi][ni][1] + bsv,
                   acc[mi][ni][2] + bsv, acc[mi][ni][3] + bsv};
      *(float4*)(&obase[s0i]) = pk;
    }
  }
}

// ---------------- launcher --------------------------------------------------
extern "C" void kernel_launch(void* const* d_in, const int* in_sizes, int n_in,
                              void* d_out, int out_size, void* d_ws,
                              size_t ws_size, hipStream_t stream) {
  const float* x = (const float*)d_in[0];
  const float* gam = (const float*)d_in[1];
  const float* bet = (const float*)d_in[2];
  const float* mu = (const float*)d_in[3];
  const float* var = (const float*)d_in[4];
  const float* wq = (const float*)d_in[5];
  const float* bq = (const float*)d_in[6];
  const float* wk = (const float*)d_in[7];
  const float* bk = (const float*)d_in[8];
  const float* wv = (const float*)d_in[9];
  const float* bv = (const float*)d_in[10];
  const float* wo = (const float*)d_in[11];
  const float* bo = (const float*)d_in[12];
  float* out = (float*)d_out;

  char* p = (char*)d_ws;
  const size_t big = (size_t)8192 * 512 * sizeof(bf16);  // 8.39 MB
  bf16* t = (bf16*)p;   p += big;  // reused as attention output o
  bf16* q = (bf16*)p;   p += big;
  bf16* k = (bf16*)p;   p += big;
  bf16* vt = (bf16*)p;  p += big;  // V already transposed [B][H][D][S]
  const size_t wsz = (size_t)512 * 512 * sizeof(bf16);
  bf16* wqb = (bf16*)p; p += wsz;
  bf16* wkb = (bf16*)p; p += wsz;
  bf16* wvb = (bf16*)p; p += wsz;
  bf16* wob = (bf16*)p; p += wsz;
  bf16* o = t;

  bn_tr_kernel<<<dim3(32, 16, 8), 256, 0, stream>>>(x, gam, bet, mu, var, t);
  wconv_kernel<<<dim3(256), 256, 0, stream>>>(wq, wk, wv, wo, wqb, wkb, wvb, wob);
  gemm_qkv_kernel<<<dim3(64, 12), 256, 0, stream>>>(t, wqb, wkb, wvb, bq, bk, bv,
                                                    q, k, vt);
  attn_kernel<<<dim3(8, 64), 512, 0, stream>>>(q, k, vt, o);
  gemm_out_kernel<<<dim3(4, 64), 256, 0, stream>>>(wob, o, bo, out);
}

// Round 5
// 87.913 us; speedup vs baseline: 1.0589x; 1.0589x over previous
//
#include <hip/hip_runtime.h>
#include <stdint.h>

typedef __bf16 bf16;
typedef bf16 bf16x8 __attribute__((ext_vector_type(8)));
typedef bf16 bf16x4 __attribute__((ext_vector_type(4)));
typedef float f32x4 __attribute__((ext_vector_type(4)));

#define NB 8
#define NS 1024
#define NC 512
#define NH 8
#define ND 64

// q pre-scale: dim_head^-0.5 * log2(e) so attention uses exp2 directly
#define QSCALE 0.18033688011f

__device__ __forceinline__ void gload16(const void* g, void* l) {
  __builtin_amdgcn_global_load_lds(
      (const __attribute__((address_space(1))) void*)g,
      (__attribute__((address_space(3))) void*)l, 16, 0, 0);
}

// ---------------- 1) BN(eval) + transpose: x[b][c][s] -> t[b][s][c] bf16 ----
__global__ __launch_bounds__(256) void bn_tr_kernel(
    const float* __restrict__ x, const float* __restrict__ gam,
    const float* __restrict__ bet, const float* __restrict__ mu,
    const float* __restrict__ var, bf16* __restrict__ t) {
  __shared__ float tile[32][33];
  const int b = blockIdx.z, c0 = blockIdx.y * 32, s0 = blockIdx.x * 32;
  const int tx = threadIdx.x, sj = tx & 31, ci = tx >> 5;
#pragma unroll
  for (int kk = 0; kk < 4; ++kk) {
    const int c = c0 + ci + (kk << 3);
    const float sc = gam[c] * rsqrtf(var[c] + 1e-5f);
    const float sh = bet[c] - mu[c] * sc;
    tile[ci + (kk << 3)][sj] = x[(size_t)(b * NC + c) * NS + s0 + sj] * sc + sh;
  }
  __syncthreads();
#pragma unroll
  for (int kk = 0; kk < 4; ++kk) {
    const int s = s0 + ci + (kk << 3);
    t[(size_t)(b * NS + s) * NC + c0 + sj] = (bf16)tile[sj][ci + (kk << 3)];
  }
}

// ---------------- 2) weights f32 -> bf16 (vectorized) -----------------------
__global__ __launch_bounds__(256) void wconv_kernel(
    const float* __restrict__ wq, const float* __restrict__ wk,
    const float* __restrict__ wv, const float* __restrict__ wo,
    bf16* __restrict__ wqb, bf16* __restrict__ wkb, bf16* __restrict__ wvb,
    bf16* __restrict__ wob) {
  const int i = (blockIdx.x * 256 + threadIdx.x) * 4;
  float4 a = *(const float4*)(&wq[i]);
  float4 b = *(const float4*)(&wk[i]);
  float4 c = *(const float4*)(&wv[i]);
  float4 d = *(const float4*)(&wo[i]);
  bf16x4 av = {(bf16)a.x, (bf16)a.y, (bf16)a.z, (bf16)a.w};
  bf16x4 bv = {(bf16)b.x, (bf16)b.y, (bf16)b.z, (bf16)b.w};
  bf16x4 cv = {(bf16)c.x, (bf16)c.y, (bf16)c.z, (bf16)c.w};
  bf16x4 dv = {(bf16)d.x, (bf16)d.y, (bf16)d.z, (bf16)d.w};
  *(bf16x4*)(&wqb[i]) = av;
  *(bf16x4*)(&wkb[i]) = bv;
  *(bf16x4*)(&wvb[i]) = cv;
  *(bf16x4*)(&wob[i]) = dv;
}

// ---------------- 3) QKV GEMM (double-buffered, XCD-swizzled) ---------------
// 1-D grid 768; lid%8 = XCD, same-m panels co-located per XCD for t-reuse.
// Q/K: swapped operands -> lane packs 4 consecutive d -> bf16x4 stores.
// V: unswapped -> lane packs 4 consecutive s -> bf16x4 stores to [B][H][D][S].
__global__ __launch_bounds__(256) void gemm_qkv_kernel(
    const bf16* __restrict__ t, const bf16* __restrict__ wqb,
    const bf16* __restrict__ wkb, const bf16* __restrict__ wvb,
    const float* __restrict__ bq, const float* __restrict__ bk,
    const float* __restrict__ bv, bf16* __restrict__ qo, bf16* __restrict__ ko,
    bf16* __restrict__ vo) {
  __shared__ __align__(16) bf16 As[2][128 * 32];
  __shared__ __align__(16) bf16 Bs[2][128 * 32];
  const int lid = blockIdx.x;
  const int xcd = lid & 7, rr = lid >> 3;        // rr in [0,96)
  const int ny = rr % 12, mx = (rr / 12) * 8 + xcd;
  const int m0 = mx << 7, n0 = ny << 7;
  const int tid = threadIdx.x;
  const int wsel = n0 >> 9;
  const bf16* W = (wsel == 0) ? wqb : (wsel == 1 ? wkb : wvb);
  const float* bias = (wsel == 0) ? bq : (wsel == 1 ? bk : bv);
  const int nb = n0 & 511;
  const int w = tid >> 6, lane = tid & 63, l15 = lane & 15, l4 = lane >> 4;
  const int wm = (w >> 1) << 6, wn = (w & 1) << 6;

  // staging geometry: linear LDS dest, inverse-swizzled global source
  const int srl = lane >> 2, sp = lane & 3;
  const int r0 = w * 16 + srl, r1 = 64 + w * 16 + srl;
  const int c0off = (sp ^ ((r0 >> 1) & 3)) << 3;
  const int c1off = (sp ^ ((r1 >> 1) & 3)) << 3;
  const bf16* a0 = t + (size_t)(m0 + r0) * 512 + c0off;
  const bf16* a1 = t + (size_t)(m0 + r1) * 512 + c1off;
  const bf16* b0 = W + (size_t)(nb + r0) * 512 + c0off;
  const bf16* b1 = W + (size_t)(nb + r1) * 512 + c1off;

  f32x4 acc[4][4] = {};
  gload16(a0, &As[0][w * 512]);
  gload16(a1, &As[0][2048 + w * 512]);
  gload16(b0, &Bs[0][w * 512]);
  gload16(b1, &Bs[0][2048 + w * 512]);
  __syncthreads();
  int buf = 0;
  for (int k0 = 0; k0 < 512; k0 += 32, buf ^= 1) {
    if (k0 + 32 < 512) {
      gload16(a0 + k0 + 32, &As[buf ^ 1][w * 512]);
      gload16(a1 + k0 + 32, &As[buf ^ 1][2048 + w * 512]);
      gload16(b0 + k0 + 32, &Bs[buf ^ 1][w * 512]);
      gload16(b1 + k0 + 32, &Bs[buf ^ 1][2048 + w * 512]);
    }
    bf16x8 af[4], bfv[4];
#pragma unroll
    for (int mi = 0; mi < 4; ++mi) {
      const int row = wm + mi * 16 + l15;
      af[mi] = *(const bf16x8*)(&As[buf][row * 32 + ((l4 ^ ((row >> 1) & 3)) << 3)]);
    }
#pragma unroll
    for (int ni = 0; ni < 4; ++ni) {
      const int row = wn + ni * 16 + l15;
      bfv[ni] = *(const bf16x8*)(&Bs[buf][row * 32 + ((l4 ^ ((row >> 1) & 3)) << 3)]);
    }
    if (wsel == 2) {
#pragma unroll
      for (int mi = 0; mi < 4; ++mi)
#pragma unroll
        for (int ni = 0; ni < 4; ++ni)
          acc[mi][ni] = __builtin_amdgcn_mfma_f32_16x16x32_bf16(
              af[mi], bfv[ni], acc[mi][ni], 0, 0, 0);
    } else {
#pragma unroll
      for (int mi = 0; mi < 4; ++mi)
#pragma unroll
        for (int ni = 0; ni < 4; ++ni)
          acc[mi][ni] = __builtin_amdgcn_mfma_f32_16x16x32_bf16(
              bfv[ni], af[mi], acc[mi][ni], 0, 0, 0);
    }
    __syncthreads();
  }
  const int bidx = m0 >> 10;
  if (wsel == 2) {
    // V (unswapped): row = s, col = l15 -> nn
    const int sbase = (m0 & 1023) + wm + (l4 << 2);
#pragma unroll
    for (int ni = 0; ni < 4; ++ni) {
      const int nn = nb + wn + ni * 16 + l15;
      const int hh = nn >> 6, dd = nn & 63;
      const float bsv = bias[nn];
      bf16* vbase = vo + (size_t)(bidx * NH + hh) * (ND * NS) + (size_t)dd * NS + sbase;
#pragma unroll
      for (int mi = 0; mi < 4; ++mi) {
        bf16x4 pk;
#pragma unroll
        for (int r = 0; r < 4; ++r) pk[r] = (bf16)(acc[mi][ni][r] + bsv);
        *(bf16x4*)(&vbase[mi * 16]) = pk;
      }
    }
  } else {
    // Q/K (swapped): row = W-dim, col = s
    const bool isq = (wsel == 0);
    bf16* outp = isq ? qo : ko;
    const int sbase = (m0 & 1023) + wm + l15;
#pragma unroll
    for (int ni = 0; ni < 4; ++ni) {
      const int nn0 = nb + wn + ni * 16 + (l4 << 2);
      const int hh = nn0 >> 6, dd0 = nn0 & 63;
      const float4 bs4 = *(const float4*)(&bias[nn0]);
      bf16* obase = outp + (size_t)(bidx * NH + hh) * (NS * ND) + dd0;
#pragma unroll
      for (int mi = 0; mi < 4; ++mi) {
        bf16x4 pk;
        const float* bp = (const float*)&bs4;
#pragma unroll
        for (int r = 0; r < 4; ++r) {
          float val = acc[mi][ni][r] + bp[r];
          if (isq) val *= QSCALE;
          pk[r] = (bf16)val;
        }
        *(bf16x4*)(&obase[(size_t)(sbase + mi * 16) * ND]) = pk;
      }
    }
  }
}

// ---------------- 4) flash attention, KVBLK=64, XCD-swizzled -----------------
// 1-D grid 512; all 8 q-tiles of a (b,h) land on one XCD -> K/V L2-resident.
// 8 waves; wave w owns q-rows [w*16, w*16+16). Swapped QK^T and swapped PV
// (O^T: lane owns q=l15 col; alpha and l are lane-local; lrun is a per-lane
// PARTIAL sum, reduced across l4 groups once at the end).
__global__ __launch_bounds__(512, 4) void attn_kernel(
    const bf16* __restrict__ qg, const bf16* __restrict__ kg,
    const bf16* __restrict__ vtg, bf16* __restrict__ og) {
  __shared__ __align__(16) bf16 Kb[2][64 * 64];  // [kv][d]
  __shared__ __align__(16) bf16 Vb[2][64 * 64];  // [d][kv]
  __shared__ __align__(16) bf16 Ps[8][16 * 64];  // per-wave P (16q x 64kv)
  const int lid = blockIdx.x;
  const int xcd = lid & 7, rr = lid >> 3;            // rr in [0,64)
  const int bh = ((rr & 7) << 3) + xcd;              // bh % 8 == xcd
  const int q0 = (rr >> 3) << 7;                     // q-tile * 128
  const int tid = threadIdx.x, w = tid >> 6, lane = tid & 63;
  const int l15 = lane & 15, l4 = lane >> 4, l7 = l15 & 7;
  const bf16* Qp = qg + ((size_t)bh * NS + q0) * ND;
  const bf16* Kp = kg + (size_t)bh * NS * ND;
  const bf16* Vp = vtg + (size_t)bh * ND * NS;

  // Q frags straight from global
  bf16x8 qf[2];
#pragma unroll
  for (int kk = 0; kk < 2; ++kk)
    qf[kk] = *(const bf16x8*)(&Qp[(size_t)(w * 16 + l15) * ND + ((kk << 2) + l4) * 8]);

  // staging: wave w stages rows [w*8, w*8+8); inverse-swizzled global source
  const int srow = w * 8 + (lane >> 3);
  const int scol = ((lane & 7) ^ (srow & 7)) << 3;
  const bf16* ksrc = Kp + (size_t)srow * ND + scol;  // + kv0*ND per tile
  const bf16* vsrc = Vp + (size_t)srow * NS + scol;  // + kv0 per tile

  f32x4 oacc[4] = {};
  float mrun = -1e30f, lrun = 0.f;

  gload16(ksrc, &Kb[0][w * 512]);
  gload16(vsrc, &Vb[0][w * 512]);
  __syncthreads();

  int buf = 0;
  for (int kv0 = 0; kv0 < NS; kv0 += 64, buf ^= 1) {
    if (kv0 + 64 < NS) {
      gload16(ksrc + (size_t)(kv0 + 64) * ND, &Kb[buf ^ 1][w * 512]);
      gload16(vsrc + (kv0 + 64), &Vb[buf ^ 1][w * 512]);
    }
    const bf16* Ks = Kb[buf];
    const bf16* Vs = Vb[buf];
    // S^T: st[rt][r] = score(kv = rt*16 + l4*4 + r, q = l15)
    f32x4 st[4];
    __builtin_amdgcn_s_setprio(1);
#pragma unroll
    for (int rt = 0; rt < 4; ++rt) {
      const int rb = (rt * 16 + l15) * 64;
      const bf16x8 a0 = *(const bf16x8*)(&Ks[rb + ((l4 ^ l7) << 3)]);
      const bf16x8 a1 = *(const bf16x8*)(&Ks[rb + (((4 + l4) ^ l7) << 3)]);
      f32x4 z = {0.f, 0.f, 0.f, 0.f};
      z = __builtin_amdgcn_mfma_f32_16x16x32_bf16(a0, qf[0], z, 0, 0, 0);
      st[rt] = __builtin_amdgcn_mfma_f32_16x16x32_bf16(a1, qf[1], z, 0, 0, 0);
    }
    __builtin_amdgcn_s_setprio(0);
    // online softmax for q-row l15 (16 in-lane + cross-l4 reduce)
    float pm = -1e30f;
#pragma unroll
    for (int rt = 0; rt < 4; ++rt)
#pragma unroll
      for (int r = 0; r < 4; ++r) pm = fmaxf(pm, st[rt][r]);
    pm = fmaxf(pm, __shfl_xor(pm, 16));
    pm = fmaxf(pm, __shfl_xor(pm, 32));
    // defer-max (T13): skip rescale while growth <= 8 (log2 domain, P <= 256)
    if (!__all(pm - mrun <= 8.f)) {
      const float mnew = fmaxf(mrun, pm);
      const float alpha = __builtin_amdgcn_exp2f(mrun - mnew);
#pragma unroll
      for (int di = 0; di < 4; ++di)
#pragma unroll
        for (int r = 0; r < 4; ++r) oacc[di][r] *= alpha;
      lrun *= alpha;
      mrun = mnew;
    }
    float rs = 0.f;
#pragma unroll
    for (int rt = 0; rt < 4; ++rt) {
      bf16x4 pk;
#pragma unroll
      for (int r = 0; r < 4; ++r) {
        const float p = __builtin_amdgcn_exp2f(st[rt][r] - mrun);
        rs += p;
        pk[r] = (bf16)p;
      }
      const int slot = (rt << 1) + (l4 >> 1);
      *(bf16x4*)(&Ps[w][l15 * 64 + ((slot ^ l7) << 3) + ((l4 & 1) << 2)]) = pk;
    }
    lrun += rs;  // per-lane partial; reduced across l4 once after the loop
    // PV (swapped): O^T[d][q] += V^T[d][kv] P[kv][q]
    const bf16x8 pa0 = *(const bf16x8*)(&Ps[w][l15 * 64 + ((l4 ^ l7) << 3)]);
    const bf16x8 pa1 = *(const bf16x8*)(&Ps[w][l15 * 64 + (((4 + l4) ^ l7) << 3)]);
    __builtin_amdgcn_s_setprio(1);
#pragma unroll
    for (int di = 0; di < 4; ++di) {
      const int vb = (di * 16 + l15) * 64;
      const bf16x8 v0 = *(const bf16x8*)(&Vs[vb + ((l4 ^ l7) << 3)]);
      const bf16x8 v1 = *(const bf16x8*)(&Vs[vb + (((4 + l4) ^ l7) << 3)]);
      oacc[di] = __builtin_amdgcn_mfma_f32_16x16x32_bf16(v0, pa0, oacc[di], 0, 0, 0);
      oacc[di] = __builtin_amdgcn_mfma_f32_16x16x32_bf16(v1, pa1, oacc[di], 0, 0, 0);
    }
    __builtin_amdgcn_s_setprio(0);
    __syncthreads();  // drains next-tile loads + protects buffer swap
  }
  lrun += __shfl_xor(lrun, 16);
  lrun += __shfl_xor(lrun, 32);
  const float linv = 1.f / lrun;
  const int b = bh >> 3, h = bh & 7;
  // O^T: lane holds q = l15 (col), d = di*16 + (l4<<2) + r -> packed bf16x4
  bf16* Op = og + (size_t)(b * NS + q0 + w * 16 + l15) * NC + h * ND + (l4 << 2);
#pragma unroll
  for (int di = 0; di < 4; ++di) {
    bf16x4 pk;
#pragma unroll
    for (int r = 0; r < 4; ++r) pk[r] = (bf16)(oacc[di][r] * linv);
    *(bf16x4*)(&Op[di * 16]) = pk;
  }
}

// ---------------- 5) out GEMM (double-buffered, swapped, XCD-swizzled) -------
// C[s][cout]: lane packs 4 consecutive s -> float4 stores to [b][cout][s].
__global__ __launch_bounds__(256) void gemm_out_kernel(
    const bf16* __restrict__ wob, const bf16* __restrict__ o,
    const float* __restrict__ bo, float* __restrict__ out) {
  __shared__ __align__(16) bf16 As[2][128 * 32];
  __shared__ __align__(16) bf16 Bs[2][128 * 32];
  const int lid = blockIdx.x;
  const int xcd = lid & 7, rr = lid >> 3;        // rr in [0,32)
  const int mx = rr & 3, ny = ((rr >> 2) << 3) + xcd;
  const int m0 = mx << 7, n0 = ny << 7;
  const int tid = threadIdx.x;
  const int w = tid >> 6, lane = tid & 63, l15 = lane & 15, l4 = lane >> 4;
  const int wm = (w >> 1) << 6, wn = (w & 1) << 6;

  const int srl = lane >> 2, sp = lane & 3;
  const int r0 = w * 16 + srl, r1 = 64 + w * 16 + srl;
  const int c0off = (sp ^ ((r0 >> 1) & 3)) << 3;
  const int c1off = (sp ^ ((r1 >> 1) & 3)) << 3;
  const bf16* a0 = wob + (size_t)(m0 + r0) * 512 + c0off;
  const bf16* a1 = wob + (size_t)(m0 + r1) * 512 + c1off;
  const bf16* b0 = o + (size_t)(n0 + r0) * 512 + c0off;
  const bf16* b1 = o + (size_t)(n0 + r1) * 512 + c1off;

  f32x4 acc[4][4] = {};
  gload16(a0, &As[0][w * 512]);
  gload16(a1, &As[0][2048 + w * 512]);
  gload16(b0, &Bs[0][w * 512]);
  gload16(b1, &Bs[0][2048 + w * 512]);
  __syncthreads();
  int buf = 0;
  for (int k0 = 0; k0 < 512; k0 += 32, buf ^= 1) {
    if (k0 + 32 < 512) {
      gload16(a0 + k0 + 32, &As[buf ^ 1][w * 512]);
      gload16(a1 + k0 + 32, &As[buf ^ 1][2048 + w * 512]);
      gload16(b0 + k0 + 32, &Bs[buf ^ 1][w * 512]);
      gload16(b1 + k0 + 32, &Bs[buf ^ 1][2048 + w * 512]);
    }
    bf16x8 af[4], bfv[4];
#pragma unroll
    for (int mi = 0; mi < 4; ++mi) {
      const int row = wm + mi * 16 + l15;
      af[mi] = *(const bf16x8*)(&As[buf][row * 32 + ((l4 ^ ((row >> 1) & 3)) << 3)]);
    }
#pragma unroll
    for (int ni = 0; ni < 4; ++ni) {
      const int row = wn + ni * 16 + l15;
      bfv[ni] = *(const bf16x8*)(&Bs[buf][row * 32 + ((l4 ^ ((row >> 1) & 3)) << 3)]);
    }
#pragma unroll
    for (int mi = 0; mi < 4; ++mi)
#pragma unroll
      for (int ni = 0; ni < 4; ++ni)
        acc[mi][ni] = __builtin_amdgcn_mfma_f32_16x16x32_bf16(
            bfv[ni], af[mi], acc[mi][ni], 0, 0, 0);
    __syncthreads();
  }
  const int b = n0 >> 10;
  const int sb = (n0 & 1023) + wn;
#pragma unroll
  for (int mi = 0; mi < 4; ++mi) {
    const int cout = m0 + wm + mi * 16 + l15;
    const float bsv = bo[cout];
    float* obase = out + (size_t)(b * NC + cout) * NS;
#pragma unroll
    for (int ni = 0; ni < 4; ++ni) {
      const int s0i = sb + ni * 16 + (l4 << 2);
      float4 pk = {acc[mi][ni][0] + bsv, acc[mi][ni][1] + bsv,
                   acc[mi][ni][2] + bsv, acc[mi][ni][3] + bsv};
      *(float4*)(&obase[s0i]) = pk;
    }
  }
}

// ---------------- launcher --------------------------------------------------
extern "C" void kernel_launch(void* const* d_in, const int* in_sizes, int n_in,
                              void* d_out, int out_size, void* d_ws,
                              size_t ws_size, hipStream_t stream) {
  const float* x = (const float*)d_in[0];
  const float* gam = (const float*)d_in[1];
  const float* bet = (const float*)d_in[2];
  const float* mu = (const float*)d_in[3];
  const float* var = (const float*)d_in[4];
  const float* wq = (const float*)d_in[5];
  const float* bq = (const float*)d_in[6];
  const float* wk = (const float*)d_in[7];
  const float* bk = (const float*)d_in[8];
  const float* wv = (const float*)d_in[9];
  const float* bv = (const float*)d_in[10];
  const float* wo = (const float*)d_in[11];
  const float* bo = (const float*)d_in[12];
  float* out = (float*)d_out;

  char* p = (char*)d_ws;
  const size_t big = (size_t)8192 * 512 * sizeof(bf16);  // 8.39 MB
  bf16* t = (bf16*)p;   p += big;  // reused as attention output o
  bf16* q = (bf16*)p;   p += big;
  bf16* k = (bf16*)p;   p += big;
  bf16* vt = (bf16*)p;  p += big;  // V already transposed [B][H][D][S]
  const size_t wsz = (size_t)512 * 512 * sizeof(bf16);
  bf16* wqb = (bf16*)p; p += wsz;
  bf16* wkb = (bf16*)p; p += wsz;
  bf16* wvb = (bf16*)p; p += wsz;
  bf16* wob = (bf16*)p; p += wsz;
  bf16* o = t;

  bn_tr_kernel<<<dim3(32, 16, 8), 256, 0, stream>>>(x, gam, bet, mu, var, t);
  wconv_kernel<<<dim3(256), 256, 0, stream>>>(wq, wk, wv, wo, wqb, wkb, wvb, wob);
  gemm_qkv_kernel<<<dim3(768), 256, 0, stream>>>(t, wqb, wkb, wvb, bq, bk, bv,
                                                 q, k, vt);
  attn_kernel<<<dim3(512), 512, 0, stream>>>(q, k, vt, o);
  gemm_out_kernel<<<dim3(256), 256, 0, stream>>>(wob, o, bo, out);
}

// Round 6
// 87.267 us; speedup vs baseline: 1.0667x; 1.0074x over previous
//
#include <hip/hip_runtime.h>
#include <stdint.h>

typedef __bf16 bf16;
typedef bf16 bf16x8 __attribute__((ext_vector_type(8)));
typedef bf16 bf16x4 __attribute__((ext_vector_type(4)));
typedef float f32x4 __attribute__((ext_vector_type(4)));

#define NB 8
#define NS 1024
#define NC 512
#define NH 8
#define ND 64

// q pre-scale: dim_head^-0.5 * log2(e) so attention uses exp2 directly
#define QSCALE 0.18033688011f

__device__ __forceinline__ void gload16(const void* g, void* l) {
  __builtin_amdgcn_global_load_lds(
      (const __attribute__((address_space(1))) void*)g,
      (__attribute__((address_space(3))) void*)l, 16, 0, 0);
}

// ---------------- 1) prep: BN+transpose (blocks 0..4095) + wconv (4096..4351)
__global__ __launch_bounds__(256) void prep_kernel(
    const float* __restrict__ x, const float* __restrict__ gam,
    const float* __restrict__ bet, const float* __restrict__ mu,
    const float* __restrict__ var, const float* __restrict__ wq,
    const float* __restrict__ wk, const float* __restrict__ wv,
    const float* __restrict__ wo, bf16* __restrict__ t, bf16* __restrict__ wqb,
    bf16* __restrict__ wkb, bf16* __restrict__ wvb, bf16* __restrict__ wob) {
  __shared__ float tile[32][33];
  const int bid = blockIdx.x;
  if (bid < 4096) {
    const int b = bid >> 9, c0 = ((bid >> 5) & 15) << 5, s0 = (bid & 31) << 5;
    const int tx = threadIdx.x, sj = tx & 31, ci = tx >> 5;
#pragma unroll
    for (int kk = 0; kk < 4; ++kk) {
      const int c = c0 + ci + (kk << 3);
      const float sc = gam[c] * rsqrtf(var[c] + 1e-5f);
      const float sh = bet[c] - mu[c] * sc;
      tile[ci + (kk << 3)][sj] = x[(size_t)(b * NC + c) * NS + s0 + sj] * sc + sh;
    }
    __syncthreads();
#pragma unroll
    for (int kk = 0; kk < 4; ++kk) {
      const int s = s0 + ci + (kk << 3);
      t[(size_t)(b * NS + s) * NC + c0 + sj] = (bf16)tile[sj][ci + (kk << 3)];
    }
  } else {
    const int i = ((bid - 4096) * 256 + threadIdx.x) * 4;
    float4 a = *(const float4*)(&wq[i]);
    float4 b = *(const float4*)(&wk[i]);
    float4 c = *(const float4*)(&wv[i]);
    float4 d = *(const float4*)(&wo[i]);
    bf16x4 av = {(bf16)a.x, (bf16)a.y, (bf16)a.z, (bf16)a.w};
    bf16x4 bv = {(bf16)b.x, (bf16)b.y, (bf16)b.z, (bf16)b.w};
    bf16x4 cv = {(bf16)c.x, (bf16)c.y, (bf16)c.z, (bf16)c.w};
    bf16x4 dv = {(bf16)d.x, (bf16)d.y, (bf16)d.z, (bf16)d.w};
    *(bf16x4*)(&wqb[i]) = av;
    *(bf16x4*)(&wkb[i]) = bv;
    *(bf16x4*)(&wvb[i]) = cv;
    *(bf16x4*)(&wob[i]) = dv;
  }
}

// ---------------- 2) QKV GEMM (double-buffered, XCD-swizzled) ---------------
// (unchanged from R5, verified)
__global__ __launch_bounds__(256) void gemm_qkv_kernel(
    const bf16* __restrict__ t, const bf16* __restrict__ wqb,
    const bf16* __restrict__ wkb, const bf16* __restrict__ wvb,
    const float* __restrict__ bq, const float* __restrict__ bk,
    const float* __restrict__ bv, bf16* __restrict__ qo, bf16* __restrict__ ko,
    bf16* __restrict__ vo) {
  __shared__ __align__(16) bf16 As[2][128 * 32];
  __shared__ __align__(16) bf16 Bs[2][128 * 32];
  const int lid = blockIdx.x;
  const int xcd = lid & 7, rr = lid >> 3;        // rr in [0,96)
  const int ny = rr % 12, mx = (rr / 12) * 8 + xcd;
  const int m0 = mx << 7, n0 = ny << 7;
  const int tid = threadIdx.x;
  const int wsel = n0 >> 9;
  const bf16* W = (wsel == 0) ? wqb : (wsel == 1 ? wkb : wvb);
  const float* bias = (wsel == 0) ? bq : (wsel == 1 ? bk : bv);
  const int nb = n0 & 511;
  const int w = tid >> 6, lane = tid & 63, l15 = lane & 15, l4 = lane >> 4;
  const int wm = (w >> 1) << 6, wn = (w & 1) << 6;

  const int srl = lane >> 2, sp = lane & 3;
  const int r0 = w * 16 + srl, r1 = 64 + w * 16 + srl;
  const int c0off = (sp ^ ((r0 >> 1) & 3)) << 3;
  const int c1off = (sp ^ ((r1 >> 1) & 3)) << 3;
  const bf16* a0 = t + (size_t)(m0 + r0) * 512 + c0off;
  const bf16* a1 = t + (size_t)(m0 + r1) * 512 + c1off;
  const bf16* b0 = W + (size_t)(nb + r0) * 512 + c0off;
  const bf16* b1 = W + (size_t)(nb + r1) * 512 + c1off;

  f32x4 acc[4][4] = {};
  gload16(a0, &As[0][w * 512]);
  gload16(a1, &As[0][2048 + w * 512]);
  gload16(b0, &Bs[0][w * 512]);
  gload16(b1, &Bs[0][2048 + w * 512]);
  __syncthreads();
  int buf = 0;
  for (int k0 = 0; k0 < 512; k0 += 32, buf ^= 1) {
    if (k0 + 32 < 512) {
      gload16(a0 + k0 + 32, &As[buf ^ 1][w * 512]);
      gload16(a1 + k0 + 32, &As[buf ^ 1][2048 + w * 512]);
      gload16(b0 + k0 + 32, &Bs[buf ^ 1][w * 512]);
      gload16(b1 + k0 + 32, &Bs[buf ^ 1][2048 + w * 512]);
    }
    bf16x8 af[4], bfv[4];
#pragma unroll
    for (int mi = 0; mi < 4; ++mi) {
      const int row = wm + mi * 16 + l15;
      af[mi] = *(const bf16x8*)(&As[buf][row * 32 + ((l4 ^ ((row >> 1) & 3)) << 3)]);
    }
#pragma unroll
    for (int ni = 0; ni < 4; ++ni) {
      const int row = wn + ni * 16 + l15;
      bfv[ni] = *(const bf16x8*)(&Bs[buf][row * 32 + ((l4 ^ ((row >> 1) & 3)) << 3)]);
    }
    if (wsel == 2) {
#pragma unroll
      for (int mi = 0; mi < 4; ++mi)
#pragma unroll
        for (int ni = 0; ni < 4; ++ni)
          acc[mi][ni] = __builtin_amdgcn_mfma_f32_16x16x32_bf16(
              af[mi], bfv[ni], acc[mi][ni], 0, 0, 0);
    } else {
#pragma unroll
      for (int mi = 0; mi < 4; ++mi)
#pragma unroll
        for (int ni = 0; ni < 4; ++ni)
          acc[mi][ni] = __builtin_amdgcn_mfma_f32_16x16x32_bf16(
              bfv[ni], af[mi], acc[mi][ni], 0, 0, 0);
    }
    __syncthreads();
  }
  const int bidx = m0 >> 10;
  if (wsel == 2) {
    const int sbase = (m0 & 1023) + wm + (l4 << 2);
#pragma unroll
    for (int ni = 0; ni < 4; ++ni) {
      const int nn = nb + wn + ni * 16 + l15;
      const int hh = nn >> 6, dd = nn & 63;
      const float bsv = bias[nn];
      bf16* vbase = vo + (size_t)(bidx * NH + hh) * (ND * NS) + (size_t)dd * NS + sbase;
#pragma unroll
      for (int mi = 0; mi < 4; ++mi) {
        bf16x4 pk;
#pragma unroll
        for (int r = 0; r < 4; ++r) pk[r] = (bf16)(acc[mi][ni][r] + bsv);
        *(bf16x4*)(&vbase[mi * 16]) = pk;
      }
    }
  } else {
    const bool isq = (wsel == 0);
    bf16* outp = isq ? qo : ko;
    const int sbase = (m0 & 1023) + wm + l15;
#pragma unroll
    for (int ni = 0; ni < 4; ++ni) {
      const int nn0 = nb + wn + ni * 16 + (l4 << 2);
      const int hh = nn0 >> 6, dd0 = nn0 & 63;
      const float4 bs4 = *(const float4*)(&bias[nn0]);
      bf16* obase = outp + (size_t)(bidx * NH + hh) * (NS * ND) + dd0;
#pragma unroll
      for (int mi = 0; mi < 4; ++mi) {
        bf16x4 pk;
        const float* bp = (const float*)&bs4;
#pragma unroll
        for (int r = 0; r < 4; ++r) {
          float val = acc[mi][ni][r] + bp[r];
          if (isq) val *= QSCALE;
          pk[r] = (bf16)val;
        }
        *(bf16x4*)(&obase[(size_t)(sbase + mi * 16) * ND]) = pk;
      }
    }
  }
}

// ---------------- 3) flash attention, KVBLK=128, chunked PV ------------------
// grid 512 (XCD-swizzled), 8 waves; wave w owns q-rows [w*16,w*16+16).
// K/V double-buffered (74 KB LDS -> 2 blocks/CU with margin). One barrier per
// 128 kv. PV in four 32-kv chunks through a small padded per-wave P buffer.
__global__ __launch_bounds__(512, 4) void attn_kernel(
    const bf16* __restrict__ qg, const bf16* __restrict__ kg,
    const bf16* __restrict__ vtg, bf16* __restrict__ og) {
  __shared__ __align__(16) bf16 Kb[2][128 * 64];  // [kv][d]  32KB
  __shared__ __align__(16) bf16 Vb[2][64 * 128];  // [d][kv]  32KB
  __shared__ __align__(16) bf16 Ps[8][16 * 40];   // padded: stride 40 elems
  const int lid = blockIdx.x;
  const int xcd = lid & 7, rr = lid >> 3;            // rr in [0,64)
  const int bh = ((rr & 7) << 3) + xcd;              // bh % 8 == xcd
  const int q0 = (rr >> 3) << 7;
  const int tid = threadIdx.x, w = tid >> 6, lane = tid & 63;
  const int l15 = lane & 15, l4 = lane >> 4;
  const bf16* Qp = qg + ((size_t)bh * NS + q0) * ND;
  const bf16* Kp = kg + (size_t)bh * NS * ND;
  const bf16* Vp = vtg + (size_t)bh * ND * NS;

  // Q frags straight from global
  bf16x8 qf[2];
#pragma unroll
  for (int kk = 0; kk < 2; ++kk)
    qf[kk] = *(const bf16x8*)(&Qp[(size_t)(w * 16 + l15) * ND + ((kk << 2) + l4) * 8]);

  // staging (inverse-swizzled global source, linear LDS dest)
  const int krow = w * 16 + (lane >> 3);           // K: rows [w*16, w*16+16)
  const bf16* ksrc = Kp + (size_t)krow * ND + (((lane & 7) ^ (krow & 7)) << 3);
  const int vrow1 = w * 8 + (lane >> 4);           // V: rows [w*8, w*8+8)
  const int vrow2 = vrow1 + 4;
  const bf16* vsrc1 = Vp + (size_t)vrow1 * NS + (((lane & 15) ^ (vrow1 & 7)) << 3);
  const bf16* vsrc2 = Vp + (size_t)vrow2 * NS + (((lane & 15) ^ (vrow2 & 7)) << 3);

  f32x4 oacc[4] = {};
  float mrun = -1e30f, lrun = 0.f;

  gload16(ksrc, &Kb[0][w * 1024]);
  gload16(ksrc + 8 * ND, &Kb[0][w * 1024 + 512]);
  gload16(vsrc1, &Vb[0][w * 1024]);
  gload16(vsrc2, &Vb[0][w * 1024 + 512]);
  __syncthreads();

  int buf = 0;
  for (int kv0 = 0; kv0 < NS; kv0 += 128, buf ^= 1) {
    if (kv0 + 128 < NS) {
      gload16(ksrc + (size_t)(kv0 + 128) * ND, &Kb[buf ^ 1][w * 1024]);
      gload16(ksrc + (size_t)(kv0 + 136) * ND, &Kb[buf ^ 1][w * 1024 + 512]);
      gload16(vsrc1 + kv0 + 128, &Vb[buf ^ 1][w * 1024]);
      gload16(vsrc2 + kv0 + 128, &Vb[buf ^ 1][w * 1024 + 512]);
    }
    const bf16* Ks = Kb[buf];
    const bf16* Vs = Vb[buf];
    // S^T: st[rt][r] = score(kv = rt*16 + l4*4 + r, q = l15)
    f32x4 st[8];
    __builtin_amdgcn_s_setprio(1);
#pragma unroll
    for (int rt = 0; rt < 8; ++rt) {
      const int row = rt * 16 + l15;
      const int rb = row * 64, s = row & 7;
      const bf16x8 a0 = *(const bf16x8*)(&Ks[rb + ((l4 ^ s) << 3)]);
      const bf16x8 a1 = *(const bf16x8*)(&Ks[rb + (((4 + l4) ^ s) << 3)]);
      f32x4 z = {0.f, 0.f, 0.f, 0.f};
      z = __builtin_amdgcn_mfma_f32_16x16x32_bf16(a0, qf[0], z, 0, 0, 0);
      st[rt] = __builtin_amdgcn_mfma_f32_16x16x32_bf16(a1, qf[1], z, 0, 0, 0);
    }
    __builtin_amdgcn_s_setprio(0);
    // online softmax for q-row l15 (32 in-lane + cross-l4 reduce)
    float pm = fmaxf(fmaxf(st[0][0], st[0][1]), fmaxf(st[0][2], st[0][3]));
#pragma unroll
    for (int rt = 1; rt < 8; ++rt)
      pm = fmaxf(pm, fmaxf(fmaxf(st[rt][0], st[rt][1]),
                           fmaxf(st[rt][2], st[rt][3])));
    pm = fmaxf(pm, __shfl_xor(pm, 16));
    pm = fmaxf(pm, __shfl_xor(pm, 32));
    // defer-max (T13)
    if (!__all(pm - mrun <= 8.f)) {
      const float mnew = fmaxf(mrun, pm);
      const float alpha = __builtin_amdgcn_exp2f(mrun - mnew);
#pragma unroll
      for (int di = 0; di < 4; ++di)
#pragma unroll
        for (int r = 0; r < 4; ++r) oacc[di][r] *= alpha;
      lrun *= alpha;
      mrun = mnew;
    }
    float rs = 0.f;
    bf16* prow = &Ps[w][l15 * 40];
    // PV in four 32-kv chunks: chunk c covers rt {2c, 2c+1}
#pragma unroll
    for (int c = 0; c < 4; ++c) {
      bf16x4 pk1, pk2;
#pragma unroll
      for (int r = 0; r < 4; ++r) {
        const float p1 = __builtin_amdgcn_exp2f(st[2 * c][r] - mrun);
        const float p2 = __builtin_amdgcn_exp2f(st[2 * c + 1][r] - mrun);
        rs += p1 + p2;
        pk1[r] = (bf16)p1;
        pk2[r] = (bf16)p2;
      }
      *(bf16x4*)(&prow[4 * l4]) = pk1;        // kv-in-chunk 4*l4 + r
      *(bf16x4*)(&prow[16 + 4 * l4]) = pk2;   // kv-in-chunk 16 + 4*l4 + r
      const bf16x8 pa = *(const bf16x8*)(&prow[l4 * 8]);
      __builtin_amdgcn_s_setprio(1);
#pragma unroll
      for (int di = 0; di < 4; ++di) {
        const int vrow = di * 16 + l15;
        const int slot = (c << 2) + l4;
        const bf16x8 vf =
            *(const bf16x8*)(&Vs[vrow * 128 + ((slot ^ (vrow & 7)) << 3)]);
        oacc[di] = __builtin_amdgcn_mfma_f32_16x16x32_bf16(vf, pa, oacc[di], 0, 0, 0);
      }
      __builtin_amdgcn_s_setprio(0);
    }
    lrun += rs;  // per-lane partial; reduced across l4 once after the loop
    __syncthreads();
  }
  lrun += __shfl_xor(lrun, 16);
  lrun += __shfl_xor(lrun, 32);
  const float linv = 1.f / lrun;
  const int b = bh >> 3, h = bh & 7;
  bf16* Op = og + (size_t)(b * NS + q0 + w * 16 + l15) * NC + h * ND + (l4 << 2);
#pragma unroll
  for (int di = 0; di < 4; ++di) {
    bf16x4 pk;
#pragma unroll
    for (int r = 0; r < 4; ++r) pk[r] = (bf16)(oacc[di][r] * linv);
    *(bf16x4*)(&Op[di * 16]) = pk;
  }
}

// ---------------- 4) out GEMM: 64x128 tiles, grid 512 (2 blocks/CU) ----------
// C[s][cout] swapped: lane packs 4 consecutive s -> float4 stores.
__global__ __launch_bounds__(256) void gemm_out_kernel(
    const bf16* __restrict__ wob, const bf16* __restrict__ o,
    const float* __restrict__ bo, float* __restrict__ out) {
  __shared__ __align__(16) bf16 As[2][64 * 32];   // 4KB each
  __shared__ __align__(16) bf16 Bs[2][128 * 32];  // 8KB each
  const int lid = blockIdx.x;
  const int xcd = lid & 7, rr = lid >> 3;              // rr in [0,64)
  const int mx = rr & 7, ny = ((rr >> 3) << 3) + xcd;  // same-ny -> same XCD
  const int m0 = mx << 6, n0 = ny << 7;
  const int tid = threadIdx.x;
  const int w = tid >> 6, lane = tid & 63, l15 = lane & 15, l4 = lane >> 4;
  const int wm = (w >> 1) << 5;  // 0 or 32 (cout)
  const int wn = (w & 1) << 6;   // 0 or 64 (s)

  const int srl = lane >> 2, sp = lane & 3;
  const int ra = w * 16 + srl;
  const int caoff = (sp ^ ((ra >> 1) & 3)) << 3;
  const bf16* a0 = wob + (size_t)(m0 + ra) * 512 + caoff;
  const int rb0 = w * 16 + srl, rb1 = 64 + w * 16 + srl;
  const int cb0off = (sp ^ ((rb0 >> 1) & 3)) << 3;
  const int cb1off = (sp ^ ((rb1 >> 1) & 3)) << 3;
  const bf16* b0 = o + (size_t)(n0 + rb0) * 512 + cb0off;
  const bf16* b1 = o + (size_t)(n0 + rb1) * 512 + cb1off;

  f32x4 acc[2][4] = {};
  gload16(a0, &As[0][w * 512]);
  gload16(b0, &Bs[0][w * 512]);
  gload16(b1, &Bs[0][2048 + w * 512]);
  __syncthreads();
  int buf = 0;
  for (int k0 = 0; k0 < 512; k0 += 32, buf ^= 1) {
    if (k0 + 32 < 512) {
      gload16(a0 + k0 + 32, &As[buf ^ 1][w * 512]);
      gload16(b0 + k0 + 32, &Bs[buf ^ 1][w * 512]);
      gload16(b1 + k0 + 32, &Bs[buf ^ 1][2048 + w * 512]);
    }
    bf16x8 af[2], bfv[4];
#pragma unroll
    for (int mi = 0; mi < 2; ++mi) {
      const int row = wm + mi * 16 + l15;
      af[mi] = *(const bf16x8*)(&As[buf][row * 32 + ((l4 ^ ((row >> 1) & 3)) << 3)]);
    }
#pragma unroll
    for (int ni = 0; ni < 4; ++ni) {
      const int row = wn + ni * 16 + l15;
      bfv[ni] = *(const bf16x8*)(&Bs[buf][row * 32 + ((l4 ^ ((row >> 1) & 3)) << 3)]);
    }
#pragma unroll
    for (int mi = 0; mi < 2; ++mi)
#pragma unroll
      for (int ni = 0; ni < 4; ++ni)
        acc[mi][ni] = __builtin_amdgcn_mfma_f32_16x16x32_bf16(
            bfv[ni], af[mi], acc[mi][ni], 0, 0, 0);
    __syncthreads();
  }
  const int b = n0 >> 10;
  const int sb = (n0 & 1023) + wn;
#pragma unroll
  for (int mi = 0; mi < 2; ++mi) {
    const int cout = m0 + wm + mi * 16 + l15;
    const float bsv = bo[cout];
    float* obase = out + (size_t)(b * NC + cout) * NS;
#pragma unroll
    for (int ni = 0; ni < 4; ++ni) {
      const int s0i = sb + ni * 16 + (l4 << 2);
      float4 pk = {acc[mi][ni][0] + bsv, acc[mi][ni][1] + bsv,
                   acc[mi][ni][2] + bsv, acc[mi][ni][3] + bsv};
      *(float4*)(&obase[s0i]) = pk;
    }
  }
}

// ---------------- launcher --------------------------------------------------
extern "C" void kernel_launch(void* const* d_in, const int* in_sizes, int n_in,
                              void* d_out, int out_size, void* d_ws,
                              size_t ws_size, hipStream_t stream) {
  const float* x = (const float*)d_in[0];
  const float* gam = (const float*)d_in[1];
  const float* bet = (const float*)d_in[2];
  const float* mu = (const float*)d_in[3];
  const float* var = (const float*)d_in[4];
  const float* wq = (const float*)d_in[5];
  const float* bq = (const float*)d_in[6];
  const float* wk = (const float*)d_in[7];
  const float* bk = (const float*)d_in[8];
  const float* wv = (const float*)d_in[9];
  const float* bv = (const float*)d_in[10];
  const float* wo = (const float*)d_in[11];
  const float* bo = (const float*)d_in[12];
  float* out = (float*)d_out;

  char* p = (char*)d_ws;
  const size_t big = (size_t)8192 * 512 * sizeof(bf16);  // 8.39 MB
  bf16* t = (bf16*)p;   p += big;  // reused as attention output o
  bf16* q = (bf16*)p;   p += big;
  bf16* k = (bf16*)p;   p += big;
  bf16* vt = (bf16*)p;  p += big;  // V already transposed [B][H][D][S]
  const size_t wsz = (size_t)512 * 512 * sizeof(bf16);
  bf16* wqb = (bf16*)p; p += wsz;
  bf16* wkb = (bf16*)p; p += wsz;
  bf16* wvb = (bf16*)p; p += wsz;
  bf16* wob = (bf16*)p; p += wsz;
  bf16* o = t;

  prep_kernel<<<dim3(4352), 256, 0, stream>>>(x, gam, bet, mu, var, wq, wk, wv,
                                              wo, t, wqb, wkb, wvb, wob);
  gemm_qkv_kernel<<<dim3(768), 256, 0, stream>>>(t, wqb, wkb, wvb, bq, bk, bv,
                                                 q, k, vt);
  attn_kernel<<<dim3(512), 512, 0, stream>>>(q, k, vt, o);
  gemm_out_kernel<<<dim3(512), 256, 0, stream>>>(wob, o, bo, out);
}

// Round 7
// 86.426 us; speedup vs baseline: 1.0771x; 1.0097x over previous
//
#include <hip/hip_runtime.h>
#include <stdint.h>

typedef __bf16 bf16;
typedef bf16 bf16x8 __attribute__((ext_vector_type(8)));
typedef bf16 bf16x4 __attribute__((ext_vector_type(4)));
typedef float f32x4 __attribute__((ext_vector_type(4)));
typedef float f32x16 __attribute__((ext_vector_type(16)));

#define NB 8
#define NS 1024
#define NC 512
#define NH 8
#define ND 64

// q pre-scale: dim_head^-0.5 * log2(e) so attention uses exp2 directly
#define QSCALE 0.18033688011f

__device__ __forceinline__ void gload16(const void* g, void* l) {
  __builtin_amdgcn_global_load_lds(
      (const __attribute__((address_space(1))) void*)g,
      (__attribute__((address_space(3))) void*)l, 16, 0, 0);
}

// pack two f32 -> one dword of 2 bf16 (compiler emits v_cvt_pk_bf16_f32)
__device__ __forceinline__ unsigned pk2(float lo, float hi) {
  union { bf16 h[2]; unsigned u; } c;
  c.h[0] = (bf16)lo;
  c.h[1] = (bf16)hi;
  return c.u;
}

// v_permlane32_swap_b32: x' = [x.lo | y.lo], y' = [x.hi | y.hi]
__device__ __forceinline__ void plswap(unsigned& x, unsigned& y) {
#if __has_builtin(__builtin_amdgcn_permlane32_swap)
  typedef unsigned uint2v __attribute__((ext_vector_type(2)));
  uint2v r = __builtin_amdgcn_permlane32_swap(x, y, false, false);
  x = r[0];
  y = r[1];
#else
  const bool hi = (threadIdx.x & 32) != 0;
  const unsigned xs = (unsigned)__shfl_xor((int)x, 32);
  const unsigned ys = (unsigned)__shfl_xor((int)y, 32);
  const unsigned nx = hi ? ys : x;
  const unsigned ny = hi ? y : xs;
  x = nx;
  y = ny;
#endif
}

// ---------------- 1) prep: BN+transpose (blocks 0..4095) + wconv (4096..4351)
__global__ __launch_bounds__(256) void prep_kernel(
    const float* __restrict__ x, const float* __restrict__ gam,
    const float* __restrict__ bet, const float* __restrict__ mu,
    const float* __restrict__ var, const float* __restrict__ wq,
    const float* __restrict__ wk, const float* __restrict__ wv,
    const float* __restrict__ wo, bf16* __restrict__ t, bf16* __restrict__ wqb,
    bf16* __restrict__ wkb, bf16* __restrict__ wvb, bf16* __restrict__ wob) {
  __shared__ float tile[32][33];
  const int bid = blockIdx.x;
  if (bid < 4096) {
    const int b = bid >> 9, c0 = ((bid >> 5) & 15) << 5, s0 = (bid & 31) << 5;
    const int tx = threadIdx.x, sj = tx & 31, ci = tx >> 5;
#pragma unroll
    for (int kk = 0; kk < 4; ++kk) {
      const int c = c0 + ci + (kk << 3);
      const float sc = gam[c] * rsqrtf(var[c] + 1e-5f);
      const float sh = bet[c] - mu[c] * sc;
      tile[ci + (kk << 3)][sj] = x[(size_t)(b * NC + c) * NS + s0 + sj] * sc + sh;
    }
    __syncthreads();
#pragma unroll
    for (int kk = 0; kk < 4; ++kk) {
      const int s = s0 + ci + (kk << 3);
      t[(size_t)(b * NS + s) * NC + c0 + sj] = (bf16)tile[sj][ci + (kk << 3)];
    }
  } else {
    const int i = ((bid - 4096) * 256 + threadIdx.x) * 4;
    float4 a = *(const float4*)(&wq[i]);
    float4 b = *(const float4*)(&wk[i]);
    float4 c = *(const float4*)(&wv[i]);
    float4 d = *(const float4*)(&wo[i]);
    bf16x4 av = {(bf16)a.x, (bf16)a.y, (bf16)a.z, (bf16)a.w};
    bf16x4 bv = {(bf16)b.x, (bf16)b.y, (bf16)b.z, (bf16)b.w};
    bf16x4 cv = {(bf16)c.x, (bf16)c.y, (bf16)c.z, (bf16)c.w};
    bf16x4 dv = {(bf16)d.x, (bf16)d.y, (bf16)d.z, (bf16)d.w};
    *(bf16x4*)(&wqb[i]) = av;
    *(bf16x4*)(&wkb[i]) = bv;
    *(bf16x4*)(&wvb[i]) = cv;
    *(bf16x4*)(&wob[i]) = dv;
  }
}

// ---------------- 2) QKV GEMM (double-buffered, XCD-swizzled) ---------------
__global__ __launch_bounds__(256) void gemm_qkv_kernel(
    const bf16* __restrict__ t, const bf16* __restrict__ wqb,
    const bf16* __restrict__ wkb, const bf16* __restrict__ wvb,
    const float* __restrict__ bq, const float* __restrict__ bk,
    const float* __restrict__ bv, bf16* __restrict__ qo, bf16* __restrict__ ko,
    bf16* __restrict__ vo) {
  __shared__ __align__(16) bf16 As[2][128 * 32];
  __shared__ __align__(16) bf16 Bs[2][128 * 32];
  const int lid = blockIdx.x;
  const int xcd = lid & 7, rr = lid >> 3;        // rr in [0,96)
  const int ny = rr % 12, mx = (rr / 12) * 8 + xcd;
  const int m0 = mx << 7, n0 = ny << 7;
  const int tid = threadIdx.x;
  const int wsel = n0 >> 9;
  const bf16* W = (wsel == 0) ? wqb : (wsel == 1 ? wkb : wvb);
  const float* bias = (wsel == 0) ? bq : (wsel == 1 ? bk : bv);
  const int nb = n0 & 511;
  const int w = tid >> 6, lane = tid & 63, l15 = lane & 15, l4 = lane >> 4;
  const int wm = (w >> 1) << 6, wn = (w & 1) << 6;

  const int srl = lane >> 2, sp = lane & 3;
  const int r0 = w * 16 + srl, r1 = 64 + w * 16 + srl;
  const int c0off = (sp ^ ((r0 >> 1) & 3)) << 3;
  const int c1off = (sp ^ ((r1 >> 1) & 3)) << 3;
  const bf16* a0 = t + (size_t)(m0 + r0) * 512 + c0off;
  const bf16* a1 = t + (size_t)(m0 + r1) * 512 + c1off;
  const bf16* b0 = W + (size_t)(nb + r0) * 512 + c0off;
  const bf16* b1 = W + (size_t)(nb + r1) * 512 + c1off;

  f32x4 acc[4][4] = {};
  gload16(a0, &As[0][w * 512]);
  gload16(a1, &As[0][2048 + w * 512]);
  gload16(b0, &Bs[0][w * 512]);
  gload16(b1, &Bs[0][2048 + w * 512]);
  __syncthreads();
  int buf = 0;
  for (int k0 = 0; k0 < 512; k0 += 32, buf ^= 1) {
    if (k0 + 32 < 512) {
      gload16(a0 + k0 + 32, &As[buf ^ 1][w * 512]);
      gload16(a1 + k0 + 32, &As[buf ^ 1][2048 + w * 512]);
      gload16(b0 + k0 + 32, &Bs[buf ^ 1][w * 512]);
      gload16(b1 + k0 + 32, &Bs[buf ^ 1][2048 + w * 512]);
    }
    bf16x8 af[4], bfv[4];
#pragma unroll
    for (int mi = 0; mi < 4; ++mi) {
      const int row = wm + mi * 16 + l15;
      af[mi] = *(const bf16x8*)(&As[buf][row * 32 + ((l4 ^ ((row >> 1) & 3)) << 3)]);
    }
#pragma unroll
    for (int ni = 0; ni < 4; ++ni) {
      const int row = wn + ni * 16 + l15;
      bfv[ni] = *(const bf16x8*)(&Bs[buf][row * 32 + ((l4 ^ ((row >> 1) & 3)) << 3)]);
    }
    if (wsel == 2) {
#pragma unroll
      for (int mi = 0; mi < 4; ++mi)
#pragma unroll
        for (int ni = 0; ni < 4; ++ni)
          acc[mi][ni] = __builtin_amdgcn_mfma_f32_16x16x32_bf16(
              af[mi], bfv[ni], acc[mi][ni], 0, 0, 0);
    } else {
#pragma unroll
      for (int mi = 0; mi < 4; ++mi)
#pragma unroll
        for (int ni = 0; ni < 4; ++ni)
          acc[mi][ni] = __builtin_amdgcn_mfma_f32_16x16x32_bf16(
              bfv[ni], af[mi], acc[mi][ni], 0, 0, 0);
    }
    __syncthreads();
  }
  const int bidx = m0 >> 10;
  if (wsel == 2) {
    const int sbase = (m0 & 1023) + wm + (l4 << 2);
#pragma unroll
    for (int ni = 0; ni < 4; ++ni) {
      const int nn = nb + wn + ni * 16 + l15;
      const int hh = nn >> 6, dd = nn & 63;
      const float bsv = bias[nn];
      bf16* vbase = vo + (size_t)(bidx * NH + hh) * (ND * NS) + (size_t)dd * NS + sbase;
#pragma unroll
      for (int mi = 0; mi < 4; ++mi) {
        bf16x4 pk;
#pragma unroll
        for (int r = 0; r < 4; ++r) pk[r] = (bf16)(acc[mi][ni][r] + bsv);
        *(bf16x4*)(&vbase[mi * 16]) = pk;
      }
    }
  } else {
    const bool isq = (wsel == 0);
    bf16* outp = isq ? qo : ko;
    const int sbase = (m0 & 1023) + wm + l15;
#pragma unroll
    for (int ni = 0; ni < 4; ++ni) {
      const int nn0 = nb + wn + ni * 16 + (l4 << 2);
      const int hh = nn0 >> 6, dd0 = nn0 & 63;
      const float4 bs4 = *(const float4*)(&bias[nn0]);
      bf16* obase = outp + (size_t)(bidx * NH + hh) * (NS * ND) + dd0;
#pragma unroll
      for (int mi = 0; mi < 4; ++mi) {
        bf16x4 pk;
        const float* bp = (const float*)&bs4;
#pragma unroll
        for (int r = 0; r < 4; ++r) {
          float val = acc[mi][ni][r] + bp[r];
          if (isq) val *= QSCALE;
          pk[r] = (bf16)val;
        }
        *(bf16x4*)(&obase[(size_t)(sbase + mi * 16) * ND]) = pk;
      }
    }
  }
}

// ---------------- 3) flash attention, 32x32 MFMA, in-register P --------------
// grid 512 (XCD-swizzled), 4 waves x QBLK=32 q-rows = 128 q/block, KVBLK=64.
// Swapped QK^T: st = mfma(K, Q) -> C[kv][q], col=q=lane&31 (lane-local
// softmax row across 2 hi-halves). P -> bf16 B-frag built in-register via
// pk2 + permlane32_swap (T12). PV: O^T = mfma(V^T, P). No P LDS.
__global__ __launch_bounds__(256, 2) void attn_kernel(
    const bf16* __restrict__ qg, const bf16* __restrict__ kg,
    const bf16* __restrict__ vtg, bf16* __restrict__ og) {
  __shared__ __align__(16) bf16 Kb[2][64 * 64];  // [kv][d]
  __shared__ __align__(16) bf16 Vb[2][64 * 64];  // [d][kv]
  const int lid = blockIdx.x;
  const int xcd = lid & 7, rr = lid >> 3;            // rr in [0,64)
  const int bh = ((rr & 7) << 3) + xcd;              // bh % 8 == xcd
  const int q0 = (rr >> 3) << 7;                     // q-tile * 128
  const int tid = threadIdx.x, w = tid >> 6, lane = tid & 63;
  const int l31 = lane & 31, hi = lane >> 5;
  const bf16* Qp = qg + ((size_t)bh * NS + q0) * ND;
  const bf16* Kp = kg + (size_t)bh * NS * ND;
  const bf16* Vp = vtg + (size_t)bh * ND * NS;

  // Q frags: B-operand of 32x32x16 -> lane holds Q[q=w*32+l31][d=16ks+8hi+j]
  bf16x8 qf0, qf1, qf2, qf3;
  {
    const bf16* qrow = Qp + (size_t)(w * 32 + l31) * ND + hi * 8;
    qf0 = *(const bf16x8*)(qrow);
    qf1 = *(const bf16x8*)(qrow + 16);
    qf2 = *(const bf16x8*)(qrow + 32);
    qf3 = *(const bf16x8*)(qrow + 48);
  }

  // staging: wave w stages rows [w*16, w*16+16) of K-tile and V-tile.
  // inverse-swizzled global source (slot ^ row&7), linear LDS dest.
  const int srow = w * 16 + (lane >> 3);
  const int sslot = (lane & 7) ^ (srow & 7);
  const bf16* ksrc = Kp + (size_t)srow * ND + sslot * 8;
  const bf16* vsrc = Vp + (size_t)srow * NS + sslot * 8;

  f32x16 oacc0 = {}, oacc1 = {};
  float mrun = -1e30f, lrun = 0.f;

  gload16(ksrc, &Kb[0][w * 1024]);
  gload16(ksrc + 8 * ND, &Kb[0][w * 1024 + 512]);   // (srow+8)&7 == srow&7
  gload16(vsrc, &Vb[0][w * 1024]);
  gload16(vsrc + 8 * NS, &Vb[0][w * 1024 + 512]);
  __syncthreads();

  const int s7 = l31 & 7;  // (32+l31)&7 == l31&7
  int buf = 0;
  for (int kv0 = 0; kv0 < NS; kv0 += 64, buf ^= 1) {
    if (kv0 + 64 < NS) {
      gload16(ksrc + (size_t)(kv0 + 64) * ND, &Kb[buf ^ 1][w * 1024]);
      gload16(ksrc + (size_t)(kv0 + 72) * ND, &Kb[buf ^ 1][w * 1024 + 512]);
      gload16(vsrc + kv0 + 64, &Vb[buf ^ 1][w * 1024]);
      gload16(vsrc + 8 * NS + kv0 + 64, &Vb[buf ^ 1][w * 1024 + 512]);
    }
    const bf16* Ks = Kb[buf];
    const bf16* Vs = Vb[buf];
    // QK^T: st0 = scores for kv 0..31 (local), st1 for 32..63; col=q=l31
    f32x16 st0 = {}, st1 = {};
    __builtin_amdgcn_s_setprio(1);
#pragma unroll
    for (int ks = 0; ks < 4; ++ks) {
      const int sl = ((2 * ks + hi) ^ s7) << 3;
      const bf16x8 a0 = *(const bf16x8*)(&Ks[l31 * 64 + sl]);
      const bf16x8 a1 = *(const bf16x8*)(&Ks[(32 + l31) * 64 + sl]);
      const bf16x8 qk = (ks == 0) ? qf0 : (ks == 1) ? qf1 : (ks == 2) ? qf2 : qf3;
      st0 = __builtin_amdgcn_mfma_f32_32x32x16_bf16(a0, qk, st0, 0, 0, 0);
      st1 = __builtin_amdgcn_mfma_f32_32x32x16_bf16(a1, qk, st1, 0, 0, 0);
    }
    __builtin_amdgcn_s_setprio(0);
    // softmax row q=l31: 32 in-lane values per hi-half + one cross-half max
    float pm = st0[0];
#pragma unroll
    for (int i = 1; i < 16; ++i) pm = fmaxf(pm, st0[i]);
#pragma unroll
    for (int i = 0; i < 16; ++i) pm = fmaxf(pm, st1[i]);
    pm = fmaxf(pm, __shfl_xor(pm, 32));
    // defer-max (T13): skip rescale while growth <= 8 (log2 domain)
    if (!__all(pm - mrun <= 8.f)) {
      const float mnew = fmaxf(mrun, pm);
      const float alpha = __builtin_amdgcn_exp2f(mrun - mnew);
#pragma unroll
      for (int i = 0; i < 16; ++i) {
        oacc0[i] *= alpha;
        oacc1[i] *= alpha;
      }
      lrun *= alpha;
      mrun = mnew;
    }
    // P + PV, one 16-kv kstep at a time. kstep t uses st[t>>1] regs
    // [8*(t&1), 8*(t&1)+8); reg i -> local k = (i&3) + 8*(i>>2) + 4*hi.
    float rs = 0.f;
#pragma unroll
    for (int t = 0; t < 4; ++t) {
      float p[8];
#pragma unroll
      for (int i = 0; i < 8; ++i) {
        const float sv = (t < 2) ? st0[8 * (t & 1) + i] : st1[8 * (t & 1) + i];
        p[i] = __builtin_amdgcn_exp2f(sv - mrun);
        rs += p[i];
      }
      // build B-frag (lane needs k = 8*hi + j): cvt_pk pairs + half-swaps
      unsigned c01 = pk2(p[0], p[1]), c23 = pk2(p[2], p[3]);
      unsigned c45 = pk2(p[4], p[5]), c67 = pk2(p[6], p[7]);
      plswap(c01, c45);  // c01 -> dw0 (j0,1), c45 -> dw2 (j4,5)
      plswap(c23, c67);  // c23 -> dw1 (j2,3), c67 -> dw3 (j6,7)
      union { unsigned u[4]; bf16x8 v; } pu;
      pu.u[0] = c01;
      pu.u[1] = c23;
      pu.u[2] = c45;
      pu.u[3] = c67;
      const int sl = ((2 * t + hi) ^ s7) << 3;
      const bf16x8 v0 = *(const bf16x8*)(&Vs[l31 * 64 + sl]);
      const bf16x8 v1 = *(const bf16x8*)(&Vs[(32 + l31) * 64 + sl]);
      __builtin_amdgcn_s_setprio(1);
      oacc0 = __builtin_amdgcn_mfma_f32_32x32x16_bf16(v0, pu.v, oacc0, 0, 0, 0);
      oacc1 = __builtin_amdgcn_mfma_f32_32x32x16_bf16(v1, pu.v, oacc1, 0, 0, 0);
      __builtin_amdgcn_s_setprio(0);
    }
    lrun += rs;  // per-lane partial (this lane's 32 kv); cross-half at end
    __syncthreads();
  }
  lrun += __shfl_xor(lrun, 32);
  const float linv = 1.f / lrun;
  const int b = bh >> 3, h = bh & 7;
  // O^T: col=q=l31 lane-local; row d = (reg&3) + 8*(reg>>2) + 4*hi (+32)
  bf16* Op = og + (size_t)(b * NS + q0 + w * 32 + l31) * NC + h * ND;
#pragma unroll
  for (int g = 0; g < 4; ++g) {
    bf16x4 pk0, pk1;
#pragma unroll
    for (int r = 0; r < 4; ++r) {
      pk0[r] = (bf16)(oacc0[4 * g + r] * linv);
      pk1[r] = (bf16)(oacc1[4 * g + r] * linv);
    }
    *(bf16x4*)(&Op[g * 8 + 4 * hi]) = pk0;
    *(bf16x4*)(&Op[32 + g * 8 + 4 * hi]) = pk1;
  }
}

// ---------------- 4) out GEMM: 64x128 tiles, grid 512 (2 blocks/CU) ----------
__global__ __launch_bounds__(256) void gemm_out_kernel(
    const bf16* __restrict__ wob, const bf16* __restrict__ o,
    const float* __restrict__ bo, float* __restrict__ out) {
  __shared__ __align__(16) bf16 As[2][64 * 32];
  __shared__ __align__(16) bf16 Bs[2][128 * 32];
  const int lid = blockIdx.x;
  const int xcd = lid & 7, rr = lid >> 3;
  const int mx = rr & 7, ny = ((rr >> 3) << 3) + xcd;
  const int m0 = mx << 6, n0 = ny << 7;
  const int tid = threadIdx.x;
  const int w = tid >> 6, lane = tid & 63, l15 = lane & 15, l4 = lane >> 4;
  const int wm = (w >> 1) << 5;
  const int wn = (w & 1) << 6;

  const int srl = lane >> 2, sp = lane & 3;
  const int ra = w * 16 + srl;
  const int caoff = (sp ^ ((ra >> 1) & 3)) << 3;
  const bf16* a0 = wob + (size_t)(m0 + ra) * 512 + caoff;
  const int rb0 = w * 16 + srl, rb1 = 64 + w * 16 + srl;
  const int cb0off = (sp ^ ((rb0 >> 1) & 3)) << 3;
  const int cb1off = (sp ^ ((rb1 >> 1) & 3)) << 3;
  const bf16* b0 = o + (size_t)(n0 + rb0) * 512 + cb0off;
  const bf16* b1 = o + (size_t)(n0 + rb1) * 512 + cb1off;

  f32x4 acc[2][4] = {};
  gload16(a0, &As[0][w * 512]);
  gload16(b0, &Bs[0][w * 512]);
  gload16(b1, &Bs[0][2048 + w * 512]);
  __syncthreads();
  int buf = 0;
  for (int k0 = 0; k0 < 512; k0 += 32, buf ^= 1) {
    if (k0 + 32 < 512) {
      gload16(a0 + k0 + 32, &As[buf ^ 1][w * 512]);
      gload16(b0 + k0 + 32, &Bs[buf ^ 1][w * 512]);
      gload16(b1 + k0 + 32, &Bs[buf ^ 1][2048 + w * 512]);
    }
    bf16x8 af[2], bfv[4];
#pragma unroll
    for (int mi = 0; mi < 2; ++mi) {
      const int row = wm + mi * 16 + l15;
      af[mi] = *(const bf16x8*)(&As[buf][row * 32 + ((l4 ^ ((row >> 1) & 3)) << 3)]);
    }
#pragma unroll
    for (int ni = 0; ni < 4; ++ni) {
      const int row = wn + ni * 16 + l15;
      bfv[ni] = *(const bf16x8*)(&Bs[buf][row * 32 + ((l4 ^ ((row >> 1) & 3)) << 3)]);
    }
#pragma unroll
    for (int mi = 0; mi < 2; ++mi)
#pragma unroll
      for (int ni = 0; ni < 4; ++ni)
        acc[mi][ni] = __builtin_amdgcn_mfma_f32_16x16x32_bf16(
            bfv[ni], af[mi], acc[mi][ni], 0, 0, 0);
    __syncthreads();
  }
  const int b = n0 >> 10;
  const int sb = (n0 & 1023) + wn;
#pragma unroll
  for (int mi = 0; mi < 2; ++mi) {
    const int cout = m0 + wm + mi * 16 + l15;
    const float bsv = bo[cout];
    float* obase = out + (size_t)(b * NC + cout) * NS;
#pragma unroll
    for (int ni = 0; ni < 4; ++ni) {
      const int s0i = sb + ni * 16 + (l4 << 2);
      float4 pk = {acc[mi][ni][0] + bsv, acc[mi][ni][1] + bsv,
                   acc[mi][ni][2] + bsv, acc[mi][ni][3] + bsv};
      *(float4*)(&obase[s0i]) = pk;
    }
  }
}

// ---------------- launcher --------------------------------------------------
extern "C" void kernel_launch(void* const* d_in, const int* in_sizes, int n_in,
                              void* d_out, int out_size, void* d_ws,
                              size_t ws_size, hipStream_t stream) {
  const float* x = (const float*)d_in[0];
  const float* gam = (const float*)d_in[1];
  const float* bet = (const float*)d_in[2];
  const float* mu = (const float*)d_in[3];
  const float* var = (const float*)d_in[4];
  const float* wq = (const float*)d_in[5];
  const float* bq = (const float*)d_in[6];
  const float* wk = (const float*)d_in[7];
  const float* bk = (const float*)d_in[8];
  const float* wv = (const float*)d_in[9];
  const float* bv = (const float*)d_in[10];
  const float* wo = (const float*)d_in[11];
  const float* bo = (const float*)d_in[12];
  float* out = (float*)d_out;

  char* p = (char*)d_ws;
  const size_t big = (size_t)8192 * 512 * sizeof(bf16);  // 8.39 MB
  bf16* t = (bf16*)p;   p += big;  // reused as attention output o
  bf16* q = (bf16*)p;   p += big;
  bf16* k = (bf16*)p;   p += big;
  bf16* vt = (bf16*)p;  p += big;  // V already transposed [B][H][D][S]
  const size_t wsz = (size_t)512 * 512 * sizeof(bf16);
  bf16* wqb = (bf16*)p; p += wsz;
  bf16* wkb = (bf16*)p; p += wsz;
  bf16* wvb = (bf16*)p; p += wsz;
  bf16* wob = (bf16*)p; p += wsz;
  bf16* o = t;

  prep_kernel<<<dim3(4352), 256, 0, stream>>>(x, gam, bet, mu, var, wq, wk, wv,
                                              wo, t, wqb, wkb, wvb, wob);
  gemm_qkv_kernel<<<dim3(768), 256, 0, stream>>>(t, wqb, wkb, wvb, bq, bk, bv,
                                                 q, k, vt);
  attn_kernel<<<dim3(512), 256, 0, stream>>>(q, k, vt, o);
  gemm_out_kernel<<<dim3(512), 256, 0, stream>>>(wob, o, bo, out);
}